// Round 13
// baseline (996.927 us; speedup 1.0000x reference)
//
#include <hip/hip_runtime.h>

#define NELEM  4
#define NMOL   64
#define NATOMS 16
#define ATOT   1024      // NMOL*NATOMS
#define REPD   256
#define NPCAS  128
#define DDIM   131072
#define PROWS  1280      // padded atom rows: 1024 + 4*63 max

typedef __attribute__((ext_vector_type(8))) short short8;   // 8 bf16 = 4 VGPR (MFMA A/B frag)
typedef __attribute__((ext_vector_type(4))) float f32x4;    // MFMA C/D frag

// bit-level bf16 (RNE) — avoids hip_bf16 API/version risk
__device__ __forceinline__ unsigned short f2bf(float x) {
    unsigned u = __builtin_bit_cast(unsigned, x);
    unsigned r = (u + 0x7FFFu + ((u >> 16) & 1u)) >> 16;
    return (unsigned short)r;
}
__device__ __forceinline__ float bf2f(unsigned short h) {
    unsigned u = ((unsigned)h) << 16;
    return __builtin_bit_cast(float, u);
}

// ---------------------------------------------------------------------------
// k_sort: stable counting-sort of atoms by element (ballot ranking), compute
// unpadded offsets goff (meta[0..4]), padded group starts pgoff (meta[5..8],
// 64-row aligned), group counts nmg (meta[9..12]); fill molid_pad (-1 = pad
// row, masked in k_main epilogue); zero out.   [validated R10]
// ---------------------------------------------------------------------------
__global__ __launch_bounds__(256)
void k_sort(const int* __restrict__ Zidx, int* __restrict__ perm,
            int* __restrict__ meta, int* __restrict__ molid_pad,
            float* __restrict__ out) {
    __shared__ int zl[ATOT];
    __shared__ int cbase[16][NELEM];
    int t = threadIdx.x;
    for (int i = t; i < ATOT; i += 256) zl[i] = Zidx[i];
    for (int i = t; i < PROWS; i += 256) molid_pad[i] = -1;
    if (t < NMOL) out[t] = 0.f;
    __syncthreads();

    int wave = t >> 6, lane = t & 63;
    for (int c = wave; c < 16; c += 4) {
        int z = zl[c * 64 + lane];
        #pragma unroll
        for (int e = 0; e < NELEM; ++e) {
            unsigned long long m = __ballot(z == e);
            if (lane == 0) cbase[c][e] = __popcll(m);
        }
    }
    __syncthreads();
    if (t == 0) {
        int off = 0, pg = 0;
        for (int e = 0; e < NELEM; ++e) {
            meta[e] = off;
            int cnt = 0;
            for (int c = 0; c < 16; ++c) { int v = cbase[c][e]; cbase[c][e] = off; off += v; cnt += v; }
            int nmg = (cnt + 63) >> 6;          // 64-row M-groups
            meta[5 + e] = pg; meta[9 + e] = nmg; pg += nmg << 6;
        }
        meta[4] = off;
    }
    __syncthreads();
    for (int c = wave; c < 16; c += 4) {
        int a = c * 64 + lane;
        int z = zl[a];
        #pragma unroll
        for (int e = 0; e < NELEM; ++e) {
            unsigned long long m = __ballot(z == e);
            if (z == e) {
                int rank = cbase[c][e] + __popcll(m & ((1ull << lane) - 1ull));
                perm[rank] = a;
                int prow = meta[5 + e] + (rank - meta[e]);
                molid_pad[prow] = a >> 4;       // mol id
            }
        }
    }
}

// ---------------------------------------------------------------------------
// k_sub: sub[i] = rep[a] @ reductors[e]  (a = perm[i]); write bf16 hi/lo
// split rows at the PADDED row index.   [validated R10]
// ---------------------------------------------------------------------------
__global__ __launch_bounds__(NPCAS)
void k_sub(const float* __restrict__ rep, const float* __restrict__ red,
           const int* __restrict__ Zidx, const int* __restrict__ perm,
           const int* __restrict__ meta,
           unsigned short* __restrict__ sub_hi, unsigned short* __restrict__ sub_lo) {
    int i = blockIdx.x;
    int p = threadIdx.x;
    int a = perm[i];                       // uniform
    int e = Zidx[a];                       // uniform
    int prow = meta[5 + e] + (i - meta[e]);
    const float* rp = rep + a * REPD;
    const float* wp = red + (size_t)(e * REPD) * NPCAS + p;
    float a0 = 0.f, a1 = 0.f, a2 = 0.f, a3 = 0.f;
    #pragma unroll 4
    for (int r = 0; r < REPD; r += 4) {
        a0 = fmaf(rp[r + 0], wp[(size_t)(r + 0) * NPCAS], a0);
        a1 = fmaf(rp[r + 1], wp[(size_t)(r + 1) * NPCAS], a1);
        a2 = fmaf(rp[r + 2], wp[(size_t)(r + 2) * NPCAS], a2);
        a3 = fmaf(rp[r + 3], wp[(size_t)(r + 3) * NPCAS], a3);
    }
    float s = (a0 + a1) + (a2 + a3);
    unsigned short h = f2bf(s);
    unsigned short l = f2bf(s - bf2f(h));
    sub_hi[prow * NPCAS + p] = h;
    sub_lo[prow * NPCAS + p] = l;
}

// ---------------------------------------------------------------------------
// k_main: R10 ran at VGPR=128 + scratch spills (WRITE_SIZE 383 MB, MfmaUtil
// 8%). Fix: (a) __launch_bounds__(256,3) -> VGPR cap ~170, 3 blocks/CU;
// (b) MFMA pass order hh -> lh -> [load bl, bh dead] -> hl cuts peak frag
// liveness 64->48 VGPRs so the hot loop fits without spilling.
// ---------------------------------------------------------------------------
__global__ __launch_bounds__(256, 3)
void k_main(const float* __restrict__ W, const float* __restrict__ bvec,
            const float* __restrict__ alpha,
            const unsigned short* __restrict__ sub_hi,
            const unsigned short* __restrict__ sub_lo,
            const int* __restrict__ molid_pad, const int* __restrict__ meta,
            float* __restrict__ out) {
    __shared__ unsigned short Bhi[64 * 128];
    __shared__ unsigned short Blo[64 * 128];
    __shared__ float outacc[NMOL];

    int t = threadIdx.x;
    int wid = t >> 6, lane = t & 63, cc = lane & 15, q = lane >> 4;
    int colbase = blockIdx.x * 64;
    if (t < NMOL) outacc[t] = 0.f;

    // alpha[col] * norm (norm = sqrt(2/131072) = 1/256), per N-subtile
    float al4[4];
    #pragma unroll
    for (int ns = 0; ns < 4; ++ns)
        al4[ns] = alpha[colbase + ns * 16 + cc] * 0.00390625f;

    int sc = t & 63;           // staging col (within wave: 64 consecutive -> coalesced)
    int kb = (t >> 6) * 32;    // staging k-base (uniform per wave)

    for (int e = 0; e < NELEM; ++e) {
        // ---- stage W[e][k][colbase+sc] -> bf16 hi/lo in LDS (swizzled) ----
        const float* Wp = W + (size_t)e * NPCAS * DDIM + colbase + sc;
        #pragma unroll
        for (int kp = 0; kp < 32; kp += 2) {
            int k = kb + kp;
            float x0 = Wp[(size_t)k * DDIM];
            float x1 = Wp[(size_t)(k + 1) * DDIM];
            unsigned short h0 = f2bf(x0), h1 = f2bf(x1);
            unsigned short l0 = f2bf(x0 - bf2f(h0)), l1 = f2bf(x1 - bf2f(h1));
            int idx = sc * 128 + (((k >> 3) ^ (sc & 7)) << 3) + (k & 7);  // even
            *reinterpret_cast<unsigned int*>(&Bhi[idx]) = (unsigned)h0 | ((unsigned)h1 << 16);
            *reinterpret_cast<unsigned int*>(&Blo[idx]) = (unsigned)l0 | ((unsigned)l1 << 16);
        }
        __syncthreads();

        float bias4[4];
        #pragma unroll
        for (int ns = 0; ns < 4; ++ns)
            bias4[ns] = bvec[(size_t)e * DDIM + colbase + ns * 16 + cc];

        int nmg   = meta[9 + e];   // 64-row groups for this element
        int prow0 = meta[5 + e];   // padded row base

        for (int mg = wid; mg < nmg; mg += 4) {
            int row0 = prow0 + mg * 64;
            f32x4 acc[4][4];
            #pragma unroll
            for (int mt = 0; mt < 4; ++mt)
                #pragma unroll
                for (int ns = 0; ns < 4; ++ns)
                    acc[mt][ns] = (f32x4){0.f, 0.f, 0.f, 0.f};

            #pragma unroll
            for (int kk = 0; kk < 4; ++kk) {
                int k = kk * 32 + q * 8;   // this lane's k-octet
                short8 ah[4], am[4], bh[4], bl[4];
                // A frags (global, L2-resident) — issue early to hide latency
                #pragma unroll
                for (int mt = 0; mt < 4; ++mt) {
                    size_t ao = (size_t)(row0 + mt * 16 + cc) * NPCAS + k;
                    ah[mt] = *reinterpret_cast<const short8*>(sub_hi + ao);
                    am[mt] = *reinterpret_cast<const short8*>(sub_lo + ao);
                }
                // B hi frags (LDS)
                #pragma unroll
                for (int ns = 0; ns < 4; ++ns) {
                    int c = ns * 16 + cc;
                    int idx = c * 128 + (((k >> 3) ^ (c & 7)) << 3);
                    bh[ns] = *reinterpret_cast<const short8*>(&Bhi[idx]);
                }
                // pass 1: hi*hi
                #pragma unroll
                for (int ns = 0; ns < 4; ++ns)
                    #pragma unroll
                    for (int mt = 0; mt < 4; ++mt)
                        acc[mt][ns] = __builtin_amdgcn_mfma_f32_16x16x32_bf16(ah[mt], bh[ns], acc[mt][ns], 0, 0, 0);
                // pass 2: lo*hi (consumes bh while live; am dead after)
                #pragma unroll
                for (int ns = 0; ns < 4; ++ns)
                    #pragma unroll
                    for (int mt = 0; mt < 4; ++mt)
                        acc[mt][ns] = __builtin_amdgcn_mfma_f32_16x16x32_bf16(am[mt], bh[ns], acc[mt][ns], 0, 0, 0);
                // B lo frags (LDS) — bh dead here, allocator can reuse its regs
                #pragma unroll
                for (int ns = 0; ns < 4; ++ns) {
                    int c = ns * 16 + cc;
                    int idx = c * 128 + (((k >> 3) ^ (c & 7)) << 3);
                    bl[ns] = *reinterpret_cast<const short8*>(&Blo[idx]);
                }
                // pass 3: hi*lo   (lo*lo dropped: ~2^-18 relative)
                #pragma unroll
                for (int ns = 0; ns < 4; ++ns)
                    #pragma unroll
                    for (int mt = 0; mt < 4; ++mt)
                        acc[mt][ns] = __builtin_amdgcn_mfma_f32_16x16x32_bf16(ah[mt], bl[ns], acc[mt][ns], 0, 0, 0);
            }

            // ---- fused epilogue: cos + alpha*norm, reduce over 16 cols ----
            float rs[4][4];
            #pragma unroll
            for (int mt = 0; mt < 4; ++mt)
                #pragma unroll
                for (int r = 0; r < 4; ++r) {
                    float s = 0.f;
                    #pragma unroll
                    for (int ns = 0; ns < 4; ++ns)
                        s += al4[ns] * __cosf(acc[mt][ns][r] + bias4[ns]);
                    rs[mt][r] = s;
                }
            #pragma unroll
            for (int mt = 0; mt < 4; ++mt)
                #pragma unroll
                for (int r = 0; r < 4; ++r) {
                    #pragma unroll
                    for (int msk = 1; msk < 16; msk <<= 1)
                        rs[mt][r] += __shfl_xor(rs[mt][r], msk, 64);
                }
            if (cc == 0) {
                #pragma unroll
                for (int mt = 0; mt < 4; ++mt)
                    #pragma unroll
                    for (int r = 0; r < 4; ++r) {
                        int m = molid_pad[row0 + mt * 16 + q * 4 + r];
                        if (m >= 0) atomicAdd(&outacc[m], rs[mt][r]);  // pad rows masked
                    }
            }
        }
        __syncthreads();   // all waves done with Bhi/Blo before next e stages
    }

    if (t < NMOL) atomicAdd(&out[t], outacc[t]);
}

// ---------------------------------------------------------------------------
extern "C" void kernel_launch(void* const* d_in, const int* in_sizes, int n_in,
                              void* d_out, int out_size, void* d_ws, size_t ws_size,
                              hipStream_t stream) {
    const float* rep   = (const float*)d_in[0];   // [64,16,256]
    const float* red   = (const float*)d_in[1];   // [4,256,128]
    const float* W     = (const float*)d_in[2];   // [4,128,131072]
    const float* bvec  = (const float*)d_in[3];   // [4,131072]
    const float* alpha = (const float*)d_in[4];   // [131072]
    const int*   Zidx  = (const int*)d_in[5];     // [64,16]
    float* out = (float*)d_out;                   // [64]

    char* ws = (char*)d_ws;
    unsigned short* sub_hi   = (unsigned short*)(ws);            // 1280*128*2 = 327680
    unsigned short* sub_lo   = (unsigned short*)(ws + 327680);   // 327680   (end 655360)
    int*            perm     = (int*)(ws + 655360);              // 4096     (end 659456)
    int*            meta     = (int*)(ws + 659456);              // 64       (end 659520)
    int*            molid    = (int*)(ws + 659520);              // 5120     (end 664640)

    k_sort<<<1, 256, 0, stream>>>(Zidx, perm, meta, molid, out);
    k_sub<<<ATOT, NPCAS, 0, stream>>>(rep, red, Zidx, perm, meta, sub_hi, sub_lo);
    k_main<<<DDIM / 64, 256, 0, stream>>>(W, bvec, alpha, sub_hi, sub_lo, molid, meta, out);
}

// Round 14
// 565.530 us; speedup vs baseline: 1.7628x; 1.7628x over previous
//
#include <hip/hip_runtime.h>

#define NELEM  4
#define NMOL   64
#define NATOMS 16
#define ATOT   1024      // NMOL*NATOMS
#define REPD   256
#define NPCAS  128
#define DDIM   131072
#define PROWS  1280      // padded atom rows: 1024 + 4*31 = 1148 max, rounded up

typedef __attribute__((ext_vector_type(8))) short short8;   // 8 bf16 = 4 VGPR (MFMA A/B frag)
typedef __attribute__((ext_vector_type(4))) float f32x4;    // MFMA C/D frag

// bit-level bf16 (RNE) — avoids hip_bf16 API/version risk
__device__ __forceinline__ unsigned short f2bf(float x) {
    unsigned u = __builtin_bit_cast(unsigned, x);
    unsigned r = (u + 0x7FFFu + ((u >> 16) & 1u)) >> 16;
    return (unsigned short)r;
}
__device__ __forceinline__ float bf2f(unsigned short h) {
    unsigned u = ((unsigned)h) << 16;
    return __builtin_bit_cast(float, u);
}

// ---------------------------------------------------------------------------
// k_sort: stable counting-sort of atoms by element (ballot ranking).
// meta[0..4] = unpadded group offsets; meta[5..8] = padded group starts
// (32-row aligned); meta[9..12] = 32-row group counts. molid_pad: -1 = pad.
// ---------------------------------------------------------------------------
__global__ __launch_bounds__(256)
void k_sort(const int* __restrict__ Zidx, int* __restrict__ perm,
            int* __restrict__ meta, int* __restrict__ molid_pad,
            float* __restrict__ out) {
    __shared__ int zl[ATOT];
    __shared__ int cbase[16][NELEM];
    int t = threadIdx.x;
    for (int i = t; i < ATOT; i += 256) zl[i] = Zidx[i];
    for (int i = t; i < PROWS; i += 256) molid_pad[i] = -1;
    if (t < NMOL) out[t] = 0.f;
    __syncthreads();

    int wave = t >> 6, lane = t & 63;
    for (int c = wave; c < 16; c += 4) {
        int z = zl[c * 64 + lane];
        #pragma unroll
        for (int e = 0; e < NELEM; ++e) {
            unsigned long long m = __ballot(z == e);
            if (lane == 0) cbase[c][e] = __popcll(m);
        }
    }
    __syncthreads();
    if (t == 0) {
        int off = 0, pg = 0;
        for (int e = 0; e < NELEM; ++e) {
            meta[e] = off;
            int cnt = 0;
            for (int c = 0; c < 16; ++c) { int v = cbase[c][e]; cbase[c][e] = off; off += v; cnt += v; }
            int nmg = (cnt + 31) >> 5;          // 32-row M-groups (acc[2][4] wave tile)
            meta[5 + e] = pg; meta[9 + e] = nmg; pg += nmg << 5;
        }
        meta[4] = off;
    }
    __syncthreads();
    for (int c = wave; c < 16; c += 4) {
        int a = c * 64 + lane;
        int z = zl[a];
        #pragma unroll
        for (int e = 0; e < NELEM; ++e) {
            unsigned long long m = __ballot(z == e);
            if (z == e) {
                int rank = cbase[c][e] + __popcll(m & ((1ull << lane) - 1ull));
                perm[rank] = a;
                int prow = meta[5 + e] + (rank - meta[e]);
                molid_pad[prow] = a >> 4;       // mol id
            }
        }
    }
}

// ---------------------------------------------------------------------------
// k_sub: sub[i] = rep[a] @ reductors[e]  (a = perm[i]); write bf16 hi/lo
// split rows at the PADDED row index.   [validated R10]
// ---------------------------------------------------------------------------
__global__ __launch_bounds__(NPCAS)
void k_sub(const float* __restrict__ rep, const float* __restrict__ red,
           const int* __restrict__ Zidx, const int* __restrict__ perm,
           const int* __restrict__ meta,
           unsigned short* __restrict__ sub_hi, unsigned short* __restrict__ sub_lo) {
    int i = blockIdx.x;
    int p = threadIdx.x;
    int a = perm[i];                       // uniform
    int e = Zidx[a];                       // uniform
    int prow = meta[5 + e] + (i - meta[e]);
    const float* rp = rep + a * REPD;
    const float* wp = red + (size_t)(e * REPD) * NPCAS + p;
    float a0 = 0.f, a1 = 0.f, a2 = 0.f, a3 = 0.f;
    #pragma unroll 4
    for (int r = 0; r < REPD; r += 4) {
        a0 = fmaf(rp[r + 0], wp[(size_t)(r + 0) * NPCAS], a0);
        a1 = fmaf(rp[r + 1], wp[(size_t)(r + 1) * NPCAS], a1);
        a2 = fmaf(rp[r + 2], wp[(size_t)(r + 2) * NPCAS], a2);
        a3 = fmaf(rp[r + 3], wp[(size_t)(r + 3) * NPCAS], a3);
    }
    float s = (a0 + a1) + (a2 + a3);
    unsigned short h = f2bf(s);
    unsigned short l = f2bf(s - bf2f(h));
    sub_hi[prow * NPCAS + p] = h;
    sub_lo[prow * NPCAS + p] = l;
}

// ---------------------------------------------------------------------------
// k_main: R10 (256,2) -> VGPR=128+spills (WRITE 383MB); R13 (256,3) -> cap
// quantized to 128, VGPR=84, MORE spills (WRITE 1.02GB). Conclusion: hipcc
// will not exceed 128 arch VGPRs here -> make the working set FIT:
// acc[2][4] (32 regs) + ah/am (16) + bh then bl staged (16) + misc ~35 = ~99.
// Wave owns 32 rows per M-group (k_sort provides 32-row groups).
// ---------------------------------------------------------------------------
__global__ __launch_bounds__(256, 2)
void k_main(const float* __restrict__ W, const float* __restrict__ bvec,
            const float* __restrict__ alpha,
            const unsigned short* __restrict__ sub_hi,
            const unsigned short* __restrict__ sub_lo,
            const int* __restrict__ molid_pad, const int* __restrict__ meta,
            float* __restrict__ out) {
    __shared__ unsigned short Bhi[64 * 128];
    __shared__ unsigned short Blo[64 * 128];
    __shared__ float outacc[NMOL];

    int t = threadIdx.x;
    int wid = t >> 6, lane = t & 63, cc = lane & 15, q = lane >> 4;
    int colbase = blockIdx.x * 64;
    if (t < NMOL) outacc[t] = 0.f;

    // alpha[col] * norm (norm = sqrt(2/131072) = 1/256), per N-subtile
    float al4[4];
    #pragma unroll
    for (int ns = 0; ns < 4; ++ns)
        al4[ns] = alpha[colbase + ns * 16 + cc] * 0.00390625f;

    int sc = t & 63;           // staging col (within wave: 64 consecutive -> coalesced)
    int kb = (t >> 6) * 32;    // staging k-base (uniform per wave)

    for (int e = 0; e < NELEM; ++e) {
        // ---- stage W[e][k][colbase+sc] -> bf16 hi/lo in LDS (swizzled) ----
        const float* Wp = W + (size_t)e * NPCAS * DDIM + colbase + sc;
        #pragma unroll
        for (int kp = 0; kp < 32; kp += 2) {
            int k = kb + kp;
            float x0 = Wp[(size_t)k * DDIM];
            float x1 = Wp[(size_t)(k + 1) * DDIM];
            unsigned short h0 = f2bf(x0), h1 = f2bf(x1);
            unsigned short l0 = f2bf(x0 - bf2f(h0)), l1 = f2bf(x1 - bf2f(h1));
            int idx = sc * 128 + (((k >> 3) ^ (sc & 7)) << 3) + (k & 7);  // even
            *reinterpret_cast<unsigned int*>(&Bhi[idx]) = (unsigned)h0 | ((unsigned)h1 << 16);
            *reinterpret_cast<unsigned int*>(&Blo[idx]) = (unsigned)l0 | ((unsigned)l1 << 16);
        }
        __syncthreads();

        float bias4[4];
        #pragma unroll
        for (int ns = 0; ns < 4; ++ns)
            bias4[ns] = bvec[(size_t)e * DDIM + colbase + ns * 16 + cc];

        int nmg   = meta[9 + e];   // 32-row groups for this element
        int prow0 = meta[5 + e];   // padded row base

        for (int mg = wid; mg < nmg; mg += 4) {
            int row0 = prow0 + mg * 32;
            f32x4 acc[2][4];
            #pragma unroll
            for (int mt = 0; mt < 2; ++mt)
                #pragma unroll
                for (int ns = 0; ns < 4; ++ns)
                    acc[mt][ns] = (f32x4){0.f, 0.f, 0.f, 0.f};

            #pragma unroll
            for (int kk = 0; kk < 4; ++kk) {
                int k = kk * 32 + q * 8;   // this lane's k-octet
                short8 ah[2], am[2], bh[4], bl[4];
                // A frags (global, L2-resident)
                #pragma unroll
                for (int mt = 0; mt < 2; ++mt) {
                    size_t ao = (size_t)(row0 + mt * 16 + cc) * NPCAS + k;
                    ah[mt] = *reinterpret_cast<const short8*>(sub_hi + ao);
                    am[mt] = *reinterpret_cast<const short8*>(sub_lo + ao);
                }
                // B hi frags (LDS)
                #pragma unroll
                for (int ns = 0; ns < 4; ++ns) {
                    int c = ns * 16 + cc;
                    int idx = c * 128 + (((k >> 3) ^ (c & 7)) << 3);
                    bh[ns] = *reinterpret_cast<const short8*>(&Bhi[idx]);
                }
                // pass 1: hi*hi
                #pragma unroll
                for (int ns = 0; ns < 4; ++ns)
                    #pragma unroll
                    for (int mt = 0; mt < 2; ++mt)
                        acc[mt][ns] = __builtin_amdgcn_mfma_f32_16x16x32_bf16(ah[mt], bh[ns], acc[mt][ns], 0, 0, 0);
                // pass 2: lo*hi (bh still live; am dead after)
                #pragma unroll
                for (int ns = 0; ns < 4; ++ns)
                    #pragma unroll
                    for (int mt = 0; mt < 2; ++mt)
                        acc[mt][ns] = __builtin_amdgcn_mfma_f32_16x16x32_bf16(am[mt], bh[ns], acc[mt][ns], 0, 0, 0);
                // B lo frags (LDS) — bh dead here, regs reusable
                #pragma unroll
                for (int ns = 0; ns < 4; ++ns) {
                    int c = ns * 16 + cc;
                    int idx = c * 128 + (((k >> 3) ^ (c & 7)) << 3);
                    bl[ns] = *reinterpret_cast<const short8*>(&Blo[idx]);
                }
                // pass 3: hi*lo   (lo*lo dropped: ~2^-18 relative)
                #pragma unroll
                for (int ns = 0; ns < 4; ++ns)
                    #pragma unroll
                    for (int mt = 0; mt < 2; ++mt)
                        acc[mt][ns] = __builtin_amdgcn_mfma_f32_16x16x32_bf16(ah[mt], bl[ns], acc[mt][ns], 0, 0, 0);
            }

            // ---- fused epilogue: cos + alpha*norm, reduce over 16 cols ----
            float rs[2][4];
            #pragma unroll
            for (int mt = 0; mt < 2; ++mt)
                #pragma unroll
                for (int r = 0; r < 4; ++r) {
                    float s = 0.f;
                    #pragma unroll
                    for (int ns = 0; ns < 4; ++ns)
                        s += al4[ns] * __cosf(acc[mt][ns][r] + bias4[ns]);
                    rs[mt][r] = s;
                }
            #pragma unroll
            for (int mt = 0; mt < 2; ++mt)
                #pragma unroll
                for (int r = 0; r < 4; ++r) {
                    #pragma unroll
                    for (int msk = 1; msk < 16; msk <<= 1)
                        rs[mt][r] += __shfl_xor(rs[mt][r], msk, 64);
                }
            if (cc == 0) {
                #pragma unroll
                for (int mt = 0; mt < 2; ++mt)
                    #pragma unroll
                    for (int r = 0; r < 4; ++r) {
                        int m = molid_pad[row0 + mt * 16 + q * 4 + r];
                        if (m >= 0) atomicAdd(&outacc[m], rs[mt][r]);  // pad rows masked
                    }
            }
        }
        __syncthreads();   // all waves done with Bhi/Blo before next e stages
    }

    if (t < NMOL) atomicAdd(&out[t], outacc[t]);
}

// ---------------------------------------------------------------------------
extern "C" void kernel_launch(void* const* d_in, const int* in_sizes, int n_in,
                              void* d_out, int out_size, void* d_ws, size_t ws_size,
                              hipStream_t stream) {
    const float* rep   = (const float*)d_in[0];   // [64,16,256]
    const float* red   = (const float*)d_in[1];   // [4,256,128]
    const float* W     = (const float*)d_in[2];   // [4,128,131072]
    const float* bvec  = (const float*)d_in[3];   // [4,131072]
    const float* alpha = (const float*)d_in[4];   // [131072]
    const int*   Zidx  = (const int*)d_in[5];     // [64,16]
    float* out = (float*)d_out;                   // [64]

    char* ws = (char*)d_ws;
    unsigned short* sub_hi   = (unsigned short*)(ws);            // 1280*128*2 = 327680
    unsigned short* sub_lo   = (unsigned short*)(ws + 327680);   // 327680   (end 655360)
    int*            perm     = (int*)(ws + 655360);              // 4096     (end 659456)
    int*            meta     = (int*)(ws + 659456);              // 64       (end 659520)
    int*            molid    = (int*)(ws + 659520);              // 5120     (end 664640)

    k_sort<<<1, 256, 0, stream>>>(Zidx, perm, meta, molid, out);
    k_sub<<<ATOT, NPCAS, 0, stream>>>(rep, red, Zidx, perm, meta, sub_hi, sub_lo);
    k_main<<<DDIM / 64, 256, 0, stream>>>(W, bvec, alpha, sub_hi, sub_lo, molid, meta, out);
}